// Round 15
// baseline (1067.681 us; speedup 1.0000x reference)
//
#include <hip/hip_runtime.h>
#include <cstdint>

// dims
#define BB   32
#define CINX 256
#define HH   56
#define WW   56
#define HWX  3136
#define CO   512
#define PL   128
#define HP   28
#define WP   28
#define HWP  784
#define NG   4
#define MSZ  7

typedef unsigned short ushortT;
typedef unsigned int   uint32;
typedef __attribute__((ext_vector_type(8))) short short8;
typedef __attribute__((ext_vector_type(4))) float f32x4;

__device__ __forceinline__ ushortT f2bf(float f){
  uint32 u = __float_as_uint(f);
  u = (u + 0x7fffu + ((u >> 16) & 1u)) >> 16;   // RNE
  return (ushortT)u;
}
__device__ __forceinline__ float bf2f(ushortT u){
  return __uint_as_float(((uint32)u) << 16);
}
__device__ __forceinline__ void split2(float v, ushortT& h, ushortT& lo){
  h = f2bf(v);
  lo = f2bf(v - bf2f(h));
}
__device__ __forceinline__ uint32 packu(ushortT a, ushortT b){
  return (uint32)a | ((uint32)b << 16);
}

// async global->LDS, 16B per lane; dest = wave-uniform base + lane*16
typedef __attribute__((address_space(1))) const void g_void;
typedef __attribute__((address_space(3))) void l_void;
__device__ __forceinline__ void glds16(const ushortT* g, ushortT* l){
  __builtin_amdgcn_global_load_lds((g_void*)g, (l_void*)l, 16, 0, 0);
}

// ============ weight prep (round-7 layout) ============
__device__ __forceinline__ void wsplit(float v, ushortT* dh, ushortT* dl, size_t i){
  ushortT h, lo; split2(v, h, lo); dh[i] = h; dl[i] = lo;
}

__global__ __launch_bounds__(256) void prep_w(
  const float* __restrict__ b_w1, const float* __restrict__ b_g1,
  const float* __restrict__ b_w2, const float* __restrict__ b_g2,
  const float* __restrict__ b_w3, const float* __restrict__ b_g3,
  const float* __restrict__ b_dw, const float* __restrict__ b_dg,
  const float* __restrict__ r_w1, const float* __restrict__ r_g1,
  const float* __restrict__ r_w2, const float* __restrict__ r_g2,
  const float* __restrict__ r_w3, const float* __restrict__ r_g3,
  const float* __restrict__ r_dw, const float* __restrict__ r_dg,
  const float* __restrict__ f_w1, const float* __restrict__ f_g1,
  const float* __restrict__ f_w2, const float* __restrict__ f_g2,
  const float* __restrict__ f_w3, const float* __restrict__ f_g3,
  const float* __restrict__ b_b1, const float* __restrict__ r_b1,
  ushortT* __restrict__ dh, ushortT* __restrict__ dl,
  ushortT* __restrict__ zp, float* __restrict__ biasC)
{
  const int idx = blockIdx.x*256 + threadIdx.x;
  switch (blockIdx.y){
    case 0: { // b1 rows 0-127 of merged
      if (idx >= 32768) return; int m = idx >> 8;
      wsplit(b_w1[idx]*b_g1[m], dh, dl, (size_t)0 + idx); } break;
    case 3: { // r1 rows 128-255 of merged
      if (idx >= 32768) return; int m = idx >> 8;
      wsplit(r_w1[idx]*r_g1[m], dh, dl, 32768 + (size_t)idx); } break;
    case 1: { // b2 [128][1152] k = tap*128+c
      if (idx >= 147456) return; int m = idx / 1152; int k = idx - m*1152;
      int tap = k >> 7, c = k & 127;
      wsplit(b_w2[((size_t)(m*128 + c))*9 + tap]*b_g2[m], dh, dl, 65536 + (size_t)idx); } break;
    case 2: { // xbase dual [512][384]
      if (idx >= 196608) return; int m = idx / 384; int k = idx - m*384;
      float v = (k < 128) ? b_w3[m*128 + k]*b_g3[m] : b_dw[m*256 + (k-128)]*b_dg[m];
      wsplit(v, dh, dl, 212992 + (size_t)idx); } break;
    case 4: { // r2 [128][1152]
      if (idx >= 147456) return; int m = idx / 1152; int k = idx - m*1152;
      int tap = k >> 7, c = k & 127;
      wsplit(r_w2[((size_t)(m*128 + c))*9 + tap]*r_g2[m], dh, dl, 409600 + (size_t)idx); } break;
    case 5: { // fuse dual [512][384]
      if (idx >= 196608) return; int m = idx / 384; int k = idx - m*384;
      float v = (k < 128) ? r_w3[m*128 + k]*r_g3[m] : r_dw[m*256 + (k-128)]*r_dg[m];
      wsplit(v, dh, dl, 557056 + (size_t)idx); } break;
    case 6: { // f1 [128][512]
      if (idx >= 65536) return; int m = idx >> 9;
      wsplit(f_w1[idx]*f_g1[m], dh, dl, 753664 + (size_t)idx); } break;
    case 7: { // f2 [128][1152]
      if (idx >= 147456) return; int m = idx / 1152; int k = idx - m*1152;
      int tap = k >> 7, c = k & 127;
      wsplit(f_w2[((size_t)(m*128 + c))*9 + tap]*f_g2[m], dh, dl, 819200 + (size_t)idx); } break;
    case 8: { // final [512][128]
      if (idx >= 65536) return; int m = idx >> 7;
      wsplit(f_w3[idx]*f_g3[m], dh, dl, 966656 + (size_t)idx); } break;
    case 9: { // zero page + concat bias
      if (idx < 64) zp[idx] = 0;
      if (idx < 128) biasC[idx] = b_b1[idx];
      else if (idx < 256) biasC[idx] = r_b1[idx-128];
    } break;
  }
}

// ============ pooled: avgpool3s2(x) NCHW f32 -> NHWC hi/lo, fused transpose ============
__global__ __launch_bounds__(256) void k_pool2(const float* __restrict__ x,
    ushortT* __restrict__ ph_, ushortT* __restrict__ pl_){
  __shared__ float s[16][17];
  const int p0 = blockIdx.x*16, c0 = blockIdx.y*16, bz = blockIdx.z;
  const int ci = threadIdx.x >> 4, pi = threadIdx.x & 15;
  {
    const int p = p0 + pi;
    const int oy = p / WP, ox = p - oy*WP;
    const float* src = x + ((size_t)bz*CINX + c0 + ci)*HWX;
    float sum = 0.f;
    #pragma unroll
    for (int dy=0; dy<3; dy++){
      int yy = 2*oy-1+dy;
      if ((unsigned)yy >= HH) continue;
      #pragma unroll
      for (int dx=0; dx<3; dx++){
        int xx = 2*ox-1+dx;
        if ((unsigned)xx >= WW) continue;
        sum += src[yy*WW + xx];
      }
    }
    s[ci][pi] = sum * (1.f/9.f);
  }
  __syncthreads();
  const int pr = threadIdx.x >> 4, cj = threadIdx.x & 15;
  float v = s[cj][pr];
  ushortT h, lo; split2(v, h, lo);
  size_t o = ((size_t)bz*HWP + p0 + pr)*CINX + c0 + cj;
  ph_[o] = h; pl_[o] = lo;
}

// ============ x f32 NCHW -> NHWC hi/lo (16x16 LDS transpose) ============
__global__ __launch_bounds__(256) void prep_x2(const float* __restrict__ x,
    ushortT* __restrict__ xh, ushortT* __restrict__ xl){
  __shared__ float s[16][17];
  const int p0 = blockIdx.x*16, c0 = blockIdx.y*16, bz = blockIdx.z;
  const int ci = threadIdx.x >> 4, pi = threadIdx.x & 15;
  s[ci][pi] = x[((size_t)bz*CINX + c0 + ci)*HWX + p0 + pi];
  __syncthreads();
  const int pr = threadIdx.x >> 4, cj = threadIdx.x & 15;
  float v = s[cj][pr];
  ushortT h, lo; split2(v, h, lo);
  size_t o = ((size_t)bz*HWX + p0 + pr)*CINX + c0 + cj;
  xh[o] = h; xl[o] = lo;
}

// ============ avgpool 3x3 s2 p1 on fused (NHWC hi/lo) -> f32 NHWC [bz][p][512] ============
__global__ __launch_bounds__(256) void k_poolf(const ushortT* __restrict__ fzh,
    const ushortT* __restrict__ fzl, float* __restrict__ pf){
  const int pb = blockIdx.x, bz = blockIdx.y;
  const int psub = threadIdx.x >> 6;
  const int lane = threadIdx.x & 63;
  const int p = pb*4 + psub;
  const int oy = p / WP, ox = p - oy*WP;
  const int c = lane*8;
  float s[8] = {0.f,0.f,0.f,0.f,0.f,0.f,0.f,0.f};
  #pragma unroll
  for (int dy=0; dy<3; dy++){
    const int iy = 2*oy - 1 + dy;
    if ((unsigned)iy >= (unsigned)HH) continue;
    #pragma unroll
    for (int dx=0; dx<3; dx++){
      const int ix = 2*ox - 1 + dx;
      if ((unsigned)ix >= (unsigned)WW) continue;
      const size_t fi = ((size_t)bz*HWX + (size_t)(iy*WW + ix))*CO + c;
      uint4 hh = *(const uint4*)(fzh + fi);
      uint4 ll = *(const uint4*)(fzl + fi);
      ushortT hv[8], lv[8];
      *(uint4*)hv = hh; *(uint4*)lv = ll;
      #pragma unroll
      for (int j=0;j<8;j++) s[j] += bf2f(hv[j]) + bf2f(lv[j]);
    }
  }
  const size_t o = ((size_t)bz*HWP + p)*CO + c;
  float4 o0 = make_float4(s[0]*(1.f/9.f), s[1]*(1.f/9.f), s[2]*(1.f/9.f), s[3]*(1.f/9.f));
  float4 o1 = make_float4(s[4]*(1.f/9.f), s[5]*(1.f/9.f), s[6]*(1.f/9.f), s[7]*(1.f/9.f));
  *(float4*)(pf + o)     = o0;
  *(float4*)(pf + o + 4) = o1;
}

// ============ unified bf16x3-split MFMA implicit-GEMM (v10: BK=64, half the barriers) ============
// DBUF==1 now means: stage TWO 32-wide K-chunks into the two 32KB buffers, one
// vmcnt(0)+barrier, compute both chunks (96 MFMA window), one barrier. 2 barriers
// per 64 K instead of 4. Same 64KB LDS -> 2 blocks/CU. Requires NK even (all are).
template<int KIND,int EPI,int S1F,int MT,int NWV,int DBUF,int SWAP,int GX,int GY,
         int STRIDE,int PAD,int HIN,int WIN,int WOUT,int NOUT,int C1,int C2,
         int BSTR1,int MTOT,int KTOT>
__global__ __launch_bounds__(NWV*64)
void gemm_bf3(const ushortT* __restrict__ wph, const ushortT* __restrict__ wpl,
              const ushortT* __restrict__ s1h, const ushortT* __restrict__ s1l,
              const ushortT* __restrict__ s2h, const ushortT* __restrict__ s2l,
              const float* __restrict__ xf32,
              const float* __restrict__ bias1, const float* __restrict__ bias2,
              const float* __restrict__ maskf, const float* __restrict__ xbase,
              const ushortT* __restrict__ zp,
              ushortT* __restrict__ oh, ushortT* __restrict__ ol,
              float* __restrict__ of32)
{
  constexpr int ACALLS  = MT/(16*NWV);   // A glds calls/wave/plane (1 or 2)
  constexpr int BCALLS2 = 8/NWV;         // B glds calls/wave/plane (1 or 2)
  constexpr bool GATHER1 = (KIND==0 && S1F==1);
  constexpr int BUFSZ = MT*64 + 8192;    // ushorts per buffer
  constexpr int WNs = (MT==256) ? 2 : (NWV==8 ? 4 : 2);
  constexpr int NF  = 128/(WNs*16);      // n-frags per wave
  constexpr int T = GX*GY*BB;
  static_assert(T % 8 == 0, "grid not divisible by 8 XCDs");
  constexpr int QX = T/8;
  __shared__ ushortT smem[BUFSZ*(DBUF+1)];

  const int tid = threadIdx.x;
  const int lin = blockIdx.x;
  const int virt = (lin & 7)*QX + (lin >> 3);        // bijective XCD-chunked remap
  const int vx = virt % GX;
  const int vrest = virt / GX;
  const int vy = vrest % GY;
  const int bz = vrest / GY;
  const int nt = SWAP ? vy : vx;
  const int mt = SWAP ? vx : vy;
  const int l  = tid & 63, w = tid >> 6;
  const int wm = w / WNs, wn = w % WNs;

  // ---- A glds precompute ----
  size_t a_src[2]; int a_dst[2];
  #pragma unroll
  for (int c=0;c<ACALLS;c++){
    int s = (w*ACALLS + c)*64 + l;
    int row = s >> 2, slotm = s & 3;
    int logical = slotm ^ ((row >> 1) & 3);
    a_src[c] = (size_t)(mt*MT + row)*KTOT + logical*8;
    a_dst[c] = (w*ACALLS + c)*512;
  }

  // ---- B glds precompute ----
  int b_dst[2]; size_t b_base1[2], b_base2[2]; int b_klane[2];
  int b_oy[2], b_ox[2]; bool b_ok[2]; float b_mv[2];
  #pragma unroll
  for (int c=0;c<BCALLS2;c++){
    int s = (w*BCALLS2 + c)*64 + l;
    int row = s >> 2, slotm = s & 3;
    int logical = slotm ^ ((row >> 1) & 3);
    b_klane[c] = logical*8;
    b_dst[c] = (w*BCALLS2 + c)*512;
    int ngr = nt*128 + row;
    b_ok[c] = (ngr < NOUT);
    int oyv = ngr / WOUT, oxv = ngr - (ngr / WOUT)*WOUT;
    b_oy[c] = oyv; b_ox[c] = oxv;
    b_base1[c] = ((size_t)bz*NOUT + ngr)*BSTR1 + b_klane[c];
    b_base2[c] = ((size_t)bz*NOUT + ngr)*C2 + b_klane[c];
    b_mv[c] = 1.f;
    if (KIND == 3)
      b_mv[c] = b_ok[c] ? maskf[((size_t)(bz*NG + mt)*MSZ + (oyv>>3))*MSZ + (oxv>>3)] : 0.f;
  }

  // ---- gather-path ids: ALL threads, 8 elems each (one 16B slot) ----
  const int g_sr = tid >> 2;
  const int g_hq = tid & 3;
  const int g_swz = (g_sr >> 1) & 3;
  const int g_lws = g_sr*32 + (g_hq ^ g_swz)*8;
  const int g_ng = nt*128 + g_sr;

  f32x4 acc[4][4];
  f32x4 zf = {0.f,0.f,0.f,0.f};
  #pragma unroll
  for (int i=0;i<4;i++)
    #pragma unroll
    for (int j=0;j<4;j++) acc[i][j] = zf;

  auto stagef = [&](int ks, ushortT* AHb, ushortT* ALb, ushortT* BHb, ushortT* BLb){
    const int k0 = ks*32;
    #pragma unroll
    for (int c=0;c<ACALLS;c++){
      glds16(wph + a_src[c] + k0, AHb + a_dst[c]);
      glds16(wpl + a_src[c] + k0, ALb + a_dst[c]);
    }
    if constexpr (GATHER1){
      uint4 bh4 = make_uint4(0,0,0,0), bl4 = bh4;
      if (g_ng < NOUT){
        size_t fbase = ((size_t)bz*C1 + k0 + g_hq*8)*(size_t)NOUT + g_ng;
        ushortT h[8], lo[8];
        #pragma unroll
        for (int e=0;e<8;e++){ split2(xf32[fbase + (size_t)e*NOUT], h[e], lo[e]); }
        bh4 = make_uint4(packu(h[0],h[1]),  packu(h[2],h[3]),  packu(h[4],h[5]),  packu(h[6],h[7]));
        bl4 = make_uint4(packu(lo[0],lo[1]),packu(lo[2],lo[3]),packu(lo[4],lo[5]),packu(lo[6],lo[7]));
      }
      *(uint4*)(BHb + g_lws) = bh4;
      *(uint4*)(BLb + g_lws) = bl4;
    } else {
      #pragma unroll
      for (int c=0;c<BCALLS2;c++){
        const ushortT *sh, *sl;
        if constexpr (KIND == 0){
          bool ok = b_ok[c];
          size_t off = b_base1[c] + k0;
          sh = ok ? s1h + off : zp;  sl = ok ? s1l + off : zp;
        } else if constexpr (KIND == 1){
          const int tap = k0 >> 7;             // C1 == 128
          const int cb  = (k0 & 127);
          const int dy = tap/3, dx = tap - 3*(tap/3);
          int iy = b_oy[c]*STRIDE + dy - PAD;
          int ix = b_ox[c]*STRIDE + dx - PAD;
          bool ok = b_ok[c] && (unsigned)iy < (unsigned)HIN && (unsigned)ix < (unsigned)WIN;
          size_t off = ((size_t)bz*(HIN*WIN) + (size_t)(iy*WIN + ix))*BSTR1 + cb + b_klane[c];
          sh = ok ? s1h + off : zp;  sl = ok ? s1l + off : zp;
        } else {
          if (k0 < C1){
            bool ok = b_ok[c] && (KIND != 3 || b_mv[c] != 0.f);
            size_t off = b_base1[c] + k0;
            sh = ok ? s1h + off : zp;  sl = ok ? s1l + off : zp;
          } else {
            bool ok = b_ok[c];
            size_t off = b_base2[c] + (k0 - C1);
            sh = ok ? s2h + off : zp;  sl = ok ? s2l + off : zp;
          }
        }
        glds16(sh, BHb + b_dst[c]);
        glds16(sl, BLb + b_dst[c]);
      }
    }
  };

  auto computef = [&](const ushortT* AHb, const ushortT* ALb,
                      const ushortT* BHb, const ushortT* BLb){
    short8 bh[NF], bl[NF];
    #pragma unroll
    for (int nf=0; nf<NF; nf++){
      const int rr = wn*(NF*16) + nf*16 + (l & 15);
      const int ph = (l >> 4) ^ ((rr >> 1) & 3);
      bh[nf] = *(const short8*)(BHb + rr*32 + ph*8);
      bl[nf] = *(const short8*)(BLb + rr*32 + ph*8);
    }
    __builtin_amdgcn_s_setprio(1);
    #pragma unroll
    for (int mf=0; mf<4; mf++){
      const int rr = wm*64 + mf*16 + (l & 15);
      const int ph = (l >> 4) ^ ((rr >> 1) & 3);
      short8 ah = *(const short8*)(AHb + rr*32 + ph*8);
      short8 al = *(const short8*)(ALb + rr*32 + ph*8);
      #pragma unroll
      for (int nf=0; nf<NF; nf++)
        acc[mf][nf] = __builtin_amdgcn_mfma_f32_16x16x32_bf16(ah, bh[nf], acc[mf][nf], 0,0,0);
      #pragma unroll
      for (int nf=0; nf<NF; nf++)
        acc[mf][nf] = __builtin_amdgcn_mfma_f32_16x16x32_bf16(ah, bl[nf], acc[mf][nf], 0,0,0);
      #pragma unroll
      for (int nf=0; nf<NF; nf++)
        acc[mf][nf] = __builtin_amdgcn_mfma_f32_16x16x32_bf16(al, bh[nf], acc[mf][nf], 0,0,0);
    }
    __builtin_amdgcn_s_setprio(0);
  };

  const int NK = KTOT / 32;
  if constexpr (DBUF == 0){
    ushortT* AH  = smem;
    ushortT* AL  = smem + MT*32;
    ushortT* BHs = smem + MT*64;
    ushortT* BLs = smem + MT*64 + 4096;
    for (int ks=0; ks<NK; ks++){
      stagef(ks, AH, AL, BHs, BLs);
      __syncthreads();
      computef(AH, AL, BHs, BLs);
      __syncthreads();
    }
  } else {
    // BK=64: stage both 32-chunks, one drain+barrier, compute both, one barrier.
    ushortT* b0 = smem;
    ushortT* b1 = smem + BUFSZ;
    for (int ks=0; ks<NK; ks+=2){
      stagef(ks,   b0, b0 + MT*32, b0 + MT*64, b0 + MT*64 + 4096);
      stagef(ks+1, b1, b1 + MT*32, b1 + MT*64, b1 + MT*64 + 4096);
      asm volatile("s_waitcnt vmcnt(0)" ::: "memory");
      __builtin_amdgcn_s_barrier();
      computef(b0, b0 + MT*32, b0 + MT*64, b0 + MT*64 + 4096);
      computef(b1, b1 + MT*32, b1 + MT*64, b1 + MT*64 + 4096);
      __builtin_amdgcn_s_barrier();
    }
  }

  // epilogue (direct stores): C/D frag col n = l&15, row m = (l>>4)*4+r
  const int mb0 = mt*MT + wm*64;
  const int nb0 = nt*128 + wn*(NF*16);

  #pragma unroll
  for (int nf=0; nf<NF; nf++){
    const int n = nb0 + nf*16 + (l & 15);
    if (n >= NOUT) continue;
    if constexpr (EPI == 0){
      const size_t ob = ((size_t)bz*NOUT + n)*MTOT;
      #pragma unroll
      for (int mf=0; mf<4; mf++){
        const int m0 = mb0 + mf*16 + (l>>4)*4;
        ushort4 hq, lq; ushortT h0, l0; float v;
        v = fmaxf(acc[mf][nf][0] + bias1[m0+0], 0.f); split2(v,h0,l0); hq.x=h0; lq.x=l0;
        v = fmaxf(acc[mf][nf][1] + bias1[m0+1], 0.f); split2(v,h0,l0); hq.y=h0; lq.y=l0;
        v = fmaxf(acc[mf][nf][2] + bias1[m0+2], 0.f); split2(v,h0,l0); hq.z=h0; lq.z=l0;
        v = fmaxf(acc[mf][nf][3] + bias1[m0+3], 0.f); split2(v,h0,l0); hq.w=h0; lq.w=l0;
        *(ushort4*)(oh + ob + m0) = hq;
        *(ushort4*)(ol + ob + m0) = lq;
      }
    } else if constexpr (EPI == 1){
      #pragma unroll
      for (int mf=0; mf<4; mf++){
        const int m0 = mb0 + mf*16 + (l>>4)*4;
        #pragma unroll
        for (int r=0;r<4;r++){
          const int m = m0 + r;
          of32[((size_t)bz*MTOT + m)*NOUT + n] = acc[mf][nf][r] + bias1[m] + bias2[m];
        }
      }
    } else if constexpr (EPI == 2){
      const int y = n / WOUT, x = n - (n / WOUT)*WOUT;
      const int grpw = (mt*MT + wm*64) >> 7;
      const float mvv = maskf[((size_t)(bz*NG + grpw)*MSZ + (y>>3))*MSZ + (x>>3)];
      const int iy = y >> 1, ix = x >> 1;
      int yA,yB,xA,xB; float wyA,wyB,wxA,wxB;
      if (y & 1){ yA=iy; wyA=0.75f; yB=(iy+1<HP)?iy+1:HP-1; wyB=0.25f; }
      else      { yA=(iy>0)?iy-1:0; wyA=0.25f; yB=iy; wyB=0.75f; }
      if (x & 1){ xA=ix; wxA=0.75f; xB=(ix+1<WP)?ix+1:WP-1; wxB=0.25f; }
      else      { xA=(ix>0)?ix-1:0; wxA=0.25f; xB=ix; wxB=0.75f; }
      const size_t ob = ((size_t)bz*NOUT + n)*MTOT;
      #pragma unroll
      for (int mf=0; mf<4; mf++){
        const int m0 = mb0 + mf*16 + (l>>4)*4;
        ushort4 hq, lq;
        #pragma unroll
        for (int r=0;r<4;r++){
          const int m = m0 + r;
          const float* xb = xbase + ((size_t)bz*MTOT + m)*HWP;
          float up = wyA*(wxA*xb[yA*WP+xA] + wxB*xb[yA*WP+xB])
                   + wyB*(wxA*xb[yB*WP+xA] + wxB*xb[yB*WP+xB]);
          float v = fmaxf(acc[mf][nf][r] + up + mvv*bias1[m] + bias2[m], 0.f);
          ushortT h0, l0; split2(v, h0, l0);
          if      (r==0){hq.x=h0;lq.x=l0;}
          else if (r==1){hq.y=h0;lq.y=l0;}
          else if (r==2){hq.z=h0;lq.z=l0;}
          else          {hq.w=h0;lq.w=l0;}
        }
        *(ushort4*)(oh + ob + m0) = hq;
        *(ushort4*)(ol + ob + m0) = lq;
      }
    } else { // EPI == 3: out = relu(acc + bias1 + pooledF[bz][n][m])
      const float* pfrow = xbase + ((size_t)bz*NOUT + n)*MTOT;
      #pragma unroll
      for (int mf=0; mf<4; mf++){
        const int m0 = mb0 + mf*16 + (l>>4)*4;
        const float4 pv = *(const float4*)(pfrow + m0);
        of32[((size_t)bz*MTOT + m0+0)*NOUT + n] = fmaxf(acc[mf][nf][0] + bias1[m0+0] + pv.x, 0.f);
        of32[((size_t)bz*MTOT + m0+1)*NOUT + n] = fmaxf(acc[mf][nf][1] + bias1[m0+1] + pv.y, 0.f);
        of32[((size_t)bz*MTOT + m0+2)*NOUT + n] = fmaxf(acc[mf][nf][2] + bias1[m0+2] + pv.z, 0.f);
        of32[((size_t)bz*MTOT + m0+3)*NOUT + n] = fmaxf(acc[mf][nf][3] + bias1[m0+3] + pv.w, 0.f);
      }
    }
  }
}

// ============ gmap v2 (round-6 proven) ============
#define GM_LDSW 9216
__global__ __launch_bounds__(256) void k_gmap2(const float* __restrict__ xbase,
    const float* __restrict__ mw, const float* __restrict__ mg, const float* __restrict__ mb,
    float* __restrict__ gmap){
  __shared__ float wsh[GM_LDSW];
  __shared__ float red[16][2][4][16];
  const int tile = blockIdx.x, b = blockIdx.y;
  const int tid = threadIdx.x;
  const int pl = tid & 15, cs = tid >> 4;
  const int p = tile*16 + pl;
  const int oy = p / WP, ox = p - oy*WP;
  int toff[9];
  #pragma unroll
  for (int tap=0; tap<9; tap++){
    int dy = tap/3, dx = tap - 3*dy;
    int yy = oy + dy - 1, xx = ox + dx - 1;
    toff[tap] = ((unsigned)yy < (unsigned)HP && (unsigned)xx < (unsigned)WP) ? (yy*WP + xx) : -1;
  }
  float acc[2][4] = {{0.f,0.f,0.f,0.f},{0.f,0.f,0.f,0.f}};
  for (int pass=0; pass<2; pass++){
    __syncthreads();
    for (int i = tid; i < GM_LDSW; i += 256){
      int ocl = i & 3, tap = (i >> 2) % 9, c_rel = i / 36;
      int cg = pass*256 + c_rel;
      int g = cg >> 7;
      int oc = g*4 + ocl;
      wsh[i] = mw[((size_t)(oc*128 + (cg & 127)))*9 + tap] * mg[oc];
    }
    __syncthreads();
    const float* xb = xbase + ((size_t)b*CO + pass*256 + cs*16)*HWP;
    for (int cl=0; cl<16; cl++){
      const float* xc = xb + (size_t)cl*HWP;
      const float* wr = &wsh[(cs*16 + cl)*36];
      #pragma unroll
      for (int tap=0; tap<9; tap++){
        if (toff[tap] < 0) continue;
        float v = xc[toff[tap]];
        f32x4 w4 = *(const f32x4*)(wr + tap*4);
        acc[pass][0] += v*w4[0];
        acc[pass][1] += v*w4[1];
        acc[pass][2] += v*w4[2];
        acc[pass][3] += v*w4[3];
      }
    }
  }
  #pragma unroll
  for (int pp=0; pp<2; pp++)
    #pragma unroll
    for (int o=0; o<4; o++)
      red[cs][pp][o][pl] = acc[pp][o];
  __syncthreads();
  const int oc = tid >> 4;
  const int g = oc >> 2, ocl = oc & 3, pg = g >> 1, cs0 = (g & 1)*8;
  float s = 0.f;
  #pragma unroll
  for (int t=0; t<8; t++) s += red[cs0 + t][pg][ocl][pl];
  s = fmaxf(s + mb[oc], 0.f);
  gmap[((size_t)b*16 + oc)*HWP + p] = s;
}

__global__ __launch_bounds__(256) void k_gpool(const float* __restrict__ gmap, float* __restrict__ gpool){
  int idx = blockIdx.x*256 + threadIdx.x;
  if (idx >= BB*16*49) return;
  int q = idx % 49; int t = idx / 49; int ch = t % 16; int b = t / 16;
  int my = q/7, mx = q%7;
  const float* src = gmap + ((size_t)b*16 + ch)*HWP;
  float s = 0.f;
  #pragma unroll
  for (int yb=0;yb<4;yb++)
    #pragma unroll
    for (int xb=0;xb<4;xb++)
      s += src[(my*4+yb)*WP + (mx*4+xb)];
  gpool[idx] = s * (1.f/16.f);
}

__global__ __launch_bounds__(256) void k_mask(const float* __restrict__ gpool, const float* __restrict__ fcw,
    const float* __restrict__ fcb, const float* __restrict__ gum,
    float* __restrict__ maskf, float* __restrict__ mout){
  int idx = blockIdx.x*256 + threadIdx.x;
  if (idx >= BB*NG*49) return;
  int q = idx % 49; int t = idx / 49; int g = t % NG; int b = t / NG;
  float lgt[2];
  #pragma unroll
  for (int cls=0; cls<2; cls++){
    int c = cls*NG + g;
    int gc = c >> 1;
    float s = fcb[c];
    #pragma unroll
    for (int k=0;k<4;k++)
      s += fcw[c*4+k] * gpool[((size_t)b*16 + gc*4 + k)*49 + q];
    s += gum[(((size_t)b*2 + cls)*NG + g)*49 + q];
    lgt[cls] = s;
  }
  float m = (lgt[1] > lgt[0]) ? 1.f : 0.f;
  maskf[idx] = m;
  mout[idx] = m;
}

extern "C" void kernel_launch(void* const* d_in, const int* in_sizes, int n_in,
                              void* d_out, int out_size, void* d_ws, size_t ws_size,
                              hipStream_t stream){
  const float* x    = (const float*)d_in[0];
  const float* gum  = (const float*)d_in[1];
  const float* b_w1 = (const float*)d_in[2];
  const float* b_g1 = (const float*)d_in[3];
  const float* b_b1 = (const float*)d_in[4];
  const float* b_w2 = (const float*)d_in[5];
  const float* b_g2 = (const float*)d_in[6];
  const float* b_b2 = (const float*)d_in[7];
  const float* b_w3 = (const float*)d_in[8];
  const float* b_g3 = (const float*)d_in[9];
  const float* b_b3 = (const float*)d_in[10];
  const float* b_dw = (const float*)d_in[11];
  const float* b_dg = (const float*)d_in[12];
  const float* b_db = (const float*)d_in[13];
  const float* r_w1 = (const float*)d_in[14];
  const float* r_g1 = (const float*)d_in[15];
  const float* r_b1 = (const float*)d_in[16];
  const float* r_w2 = (const float*)d_in[17];
  const float* r_g2 = (const float*)d_in[18];
  const float* r_b2 = (const float*)d_in[19];
  const float* r_w3 = (const float*)d_in[20];
  const float* r_g3 = (const float*)d_in[21];
  const float* r_b3 = (const float*)d_in[22];
  const float* r_dw = (const float*)d_in[23];
  const float* r_dg = (const float*)d_in[24];
  const float* r_db = (const float*)d_in[25];
  const float* m_w  = (const float*)d_in[26];
  const float* m_g  = (const float*)d_in[27];
  const float* m_b  = (const float*)d_in[28];
  const float* m_fcw= (const float*)d_in[29];
  const float* m_fcb= (const float*)d_in[30];
  const float* f_w1 = (const float*)d_in[31];
  const float* f_g1 = (const float*)d_in[32];
  const float* f_b1 = (const float*)d_in[33];
  const float* f_w2 = (const float*)d_in[34];
  const float* f_g2 = (const float*)d_in[35];
  const float* f_b2 = (const float*)d_in[36];
  const float* f_w3 = (const float*)d_in[37];
  const float* f_g3 = (const float*)d_in[38];
  const float* f_b3 = (const float*)d_in[39];

  char* ws = (char*)d_ws;
  // ws layout v5 — total 378,367,616 B
  constexpr size_t O_WPH  = 0;            //  2,064,384
  constexpr size_t O_WPL  = 2064384;      //  2,064,384  -> 4,128,768
  constexpr size_t O_CH   = 4128768;      // 51,380,224  merged hi; then XH (x hi NHWC); then f1 hi+lo
  constexpr size_t O_DH   = 55508992;     //  6,422,528  t2/f2 hi
  constexpr size_t O_DL   = 61931520;     //  6,422,528  -> 68,354,048
  constexpr size_t O_EH   = 68354048;     // 25,690,112  r2 hi
  constexpr size_t O_EL   = 94044160;     // 25,690,112  -> 119,734,272
  constexpr size_t O_PF   = O_EH;         // 51,380,224  pooledF f32 NHWC (r2 dead after fuse)
  constexpr size_t O_XB   = 119734272;    // 51,380,224  xbase f32 NCHW
  constexpr size_t O_GMAP = 171114496;    //  1,605,632
  constexpr size_t O_GPOOL= 172720128;    //    100,352
  constexpr size_t O_MASK = 172820480;    //     25,088
  constexpr size_t O_FH   = 172845568;    // 102,760,448 fused hi (overlaps PH/PL)
  constexpr size_t O_PH   = 172845568;    // 12,845,056  pooled hi (dead after xbase GEMM)
  constexpr size_t O_PL   = 185690624;    // 12,845,056
  constexpr size_t O_FL   = 275606016;    // 102,760,448 -> 378,366,464
  constexpr size_t O_ZP   = 378366464;    //        128  zero page
  constexpr size_t O_BIASC= 378366592;    //      1,024  concat bias -> 378,367,616

  ushortT* WPH = (ushortT*)(ws + O_WPH);
  ushortT* WPL = (ushortT*)(ws + O_WPL);
  ushortT* MGH = (ushortT*)(ws + O_CH);          // merged hi plane, stride 256 (b2/r2 input)
  ushortT* XH  = (ushortT*)(ws + O_CH);          // x hi NHWC (after r2; fuse input)
  ushortT* F1H = (ushortT*)(ws + O_CH);          // f1 hi (after fuse)
  ushortT* F1L = (ushortT*)(ws + O_CH + 25690112);
  ushortT* DHp = (ushortT*)(ws + O_DH);
  ushortT* DLp = (ushortT*)(ws + O_DL);
  ushortT* EHp = (ushortT*)(ws + O_EH);
  ushortT* ELp = (ushortT*)(ws + O_EL);
  float*   PF  = (float*)(ws + O_PF);
  float*   XB  = (float*)(ws + O_XB);
  ushortT* PHp = (ushortT*)(ws + O_PH);
  ushortT* PLp = (ushortT*)(ws + O_PL);
  ushortT* FHp = (ushortT*)(ws + O_FH);
  ushortT* FLp = (ushortT*)(ws + O_FL);
  float*   GMAP = (float*)(ws + O_GMAP);
  float*   GPOOL= (float*)(ws + O_GPOOL);
  float*   MASKF= (float*)(ws + O_MASK);
  ushortT* ZP  = (ushortT*)(ws + O_ZP);
  float*   BIASC = (float*)(ws + O_BIASC);
  (void)ws_size;

  float* outp = (float*)d_out;
  float* mout = outp + (size_t)BB*CO*HWP;
  ushortT* dout_u = (ushortT*)d_out;             // merged lo plane, then XL (x lo NHWC)

  dim3 blk(256), blk512(512);
  const ushortT* nu = nullptr; const float* nf_ = nullptr;
  ushortT* nuo = nullptr; float* nfo = nullptr;

  // prep
  prep_w<<<dim3(768, 10), blk, 0, stream>>>(b_w1,b_g1,b_w2,b_g2,b_w3,b_g3,b_dw,b_dg,
      r_w1,r_g1,r_w2,r_g2,r_w3,r_g3,r_dw,r_dg,f_w1,f_g1,f_w2,f_g2,f_w3,f_g3,
      b_b1, r_b1, WPH, WPL, ZP, BIASC);
  k_pool2<<<dim3(49, 16, BB), blk, 0, stream>>>(x, PHp, PLp);

  // merged b1|r1: one x-gather pass (spread over 512 threads), MT=256, 8 waves  T=800
  gemm_bf3<0,0,1,256,8,0,0, 25,1, 1,0,56,56,56,3136, 256,0,256, 256,256><<<dim3(800), blk512, 0, stream>>>(
      WPH+0, WPL+0, nu, nu, nu, nu, x, BIASC, nf_, nf_, nf_, ZP, MGH, dout_u, nfo);
  // b2 — MT=128, 4 waves, BK=64  T=224
  gemm_bf3<1,0,0,128,4,1,0, 7,1, 2,1,56,56,28,784, 128,0,256, 128,1152><<<dim3(224), blk, 0, stream>>>(
      WPH+65536, WPL+65536, MGH, dout_u, nu, nu, nf_, b_b2, nf_, nf_, nf_, ZP, DHp, DLp, nfo);
  // xbase dual — MT=256, 8 waves, single-buffer  T=448
  gemm_bf3<2,1,0,256,8,0,0, 7,2, 1,0,28,28,28,784, 128,256,128, 512,384><<<dim3(448), blk512, 0, stream>>>(
      WPH+212992, WPL+212992, DHp, DLp, PHp, PLp, nf_, b_b3, b_db, nf_, nf_, ZP, nuo, nuo, XB);

  // mask path
  k_gmap2<<<dim3(49, BB), blk, 0, stream>>>(XB, m_w, m_g, m_b, GMAP);
  k_gpool<<<dim3(98), blk, 0, stream>>>(GMAP, GPOOL);
  k_mask<<<dim3(25), blk, 0, stream>>>(GPOOL, m_fcw, m_fcb, gum, MASKF, mout);

  // r2 — MT=128, 4 waves, BK=64  T=800
  gemm_bf3<1,0,0,128,4,1,0, 25,1, 1,1,56,56,56,3136, 128,0,256, 128,1152><<<dim3(800), blk, 0, stream>>>(
      WPH+409600, WPL+409600, MGH+128, dout_u+128, nu, nu, nf_, r_b2, nf_, nf_, nf_, ZP, EHp, ELp, nfo);

  // pre-split x -> XH (CH region, merged dead) + XL (d_out, merged-lo dead)
  prep_x2<<<dim3(196, 16, BB), blk, 0, stream>>>(x, XH, dout_u);

  // fused — MT=128, 4 waves, BK=64, mt-fastest  T=3200
  gemm_bf3<3,2,0,128,4,1,1, 4,25, 1,0,56,56,56,3136, 128,256,128, 512,384><<<dim3(3200), blk, 0, stream>>>(
      WPH+557056, WPL+557056, EHp, ELp, XH, dout_u, nf_, r_b3, r_db, MASKF, XB, ZP, FHp, FLp, nfo);

  // pooledF = avgpool3s2(fused)
  k_poolf<<<dim3(196, BB), blk, 0, stream>>>(FHp, FLp, PF);

  // fuse branch
  gemm_bf3<0,0,0,128,4,1,0, 25,1, 1,0,56,56,56,3136, 512,0,512, 128,512><<<dim3(800), blk, 0, stream>>>(
      WPH+753664, WPL+753664, FHp, FLp, nu, nu, nf_, f_b1, nf_, nf_, nf_, ZP, F1H, F1L, nfo);
  gemm_bf3<1,0,0,128,4,1,0, 7,1, 2,1,56,56,28,784, 128,0,128, 128,1152><<<dim3(224), blk, 0, stream>>>(
      WPH+819200, WPL+819200, F1H, F1L, nu, nu, nf_, f_b2, nf_, nf_, nf_, ZP, DHp, DLp, nfo);
  // final — MT=256, 8 waves, single-buffer  T=448
  gemm_bf3<0,3,0,256,8,0,0, 7,2, 1,0,28,28,28,784, 128,0,128, 512,128><<<dim3(448), blk512, 0, stream>>>(
      WPH+966656, WPL+966656, DHp, DLp, nu, nu, nf_, f_b3, nf_, nf_, PF, ZP, nuo, nuo, outp);
}

// Round 16
// 1045.349 us; speedup vs baseline: 1.0214x; 1.0214x over previous
//
#include <hip/hip_runtime.h>
#include <cstdint>

// dims
#define BB   32
#define CINX 256
#define HH   56
#define WW   56
#define HWX  3136
#define CO   512
#define PL   128
#define HP   28
#define WP   28
#define HWP  784
#define NG   4
#define MSZ  7

typedef unsigned short ushortT;
typedef unsigned int   uint32;
typedef __attribute__((ext_vector_type(8))) short short8;
typedef __attribute__((ext_vector_type(4))) float f32x4;

__device__ __forceinline__ ushortT f2bf(float f){
  uint32 u = __float_as_uint(f);
  u = (u + 0x7fffu + ((u >> 16) & 1u)) >> 16;   // RNE
  return (ushortT)u;
}
__device__ __forceinline__ float bf2f(ushortT u){
  return __uint_as_float(((uint32)u) << 16);
}
__device__ __forceinline__ void split2(float v, ushortT& h, ushortT& lo){
  h = f2bf(v);
  lo = f2bf(v - bf2f(h));
}
__device__ __forceinline__ uint32 packu(ushortT a, ushortT b){
  return (uint32)a | ((uint32)b << 16);
}

// async global->LDS, 16B per lane; dest = wave-uniform base + lane*16
typedef __attribute__((address_space(1))) const void g_void;
typedef __attribute__((address_space(3))) void l_void;
__device__ __forceinline__ void glds16(const ushortT* g, ushortT* l){
  __builtin_amdgcn_global_load_lds((g_void*)g, (l_void*)l, 16, 0, 0);
}

// ============ weight prep (round-7 layout) ============
__device__ __forceinline__ void wsplit(float v, ushortT* dh, ushortT* dl, size_t i){
  ushortT h, lo; split2(v, h, lo); dh[i] = h; dl[i] = lo;
}

__global__ __launch_bounds__(256) void prep_w(
  const float* __restrict__ b_w1, const float* __restrict__ b_g1,
  const float* __restrict__ b_w2, const float* __restrict__ b_g2,
  const float* __restrict__ b_w3, const float* __restrict__ b_g3,
  const float* __restrict__ b_dw, const float* __restrict__ b_dg,
  const float* __restrict__ r_w1, const float* __restrict__ r_g1,
  const float* __restrict__ r_w2, const float* __restrict__ r_g2,
  const float* __restrict__ r_w3, const float* __restrict__ r_g3,
  const float* __restrict__ r_dw, const float* __restrict__ r_dg,
  const float* __restrict__ f_w1, const float* __restrict__ f_g1,
  const float* __restrict__ f_w2, const float* __restrict__ f_g2,
  const float* __restrict__ f_w3, const float* __restrict__ f_g3,
  const float* __restrict__ b_b1, const float* __restrict__ r_b1,
  ushortT* __restrict__ dh, ushortT* __restrict__ dl,
  ushortT* __restrict__ zp, float* __restrict__ biasC)
{
  const int idx = blockIdx.x*256 + threadIdx.x;
  switch (blockIdx.y){
    case 0: { // b1 rows 0-127 of merged
      if (idx >= 32768) return; int m = idx >> 8;
      wsplit(b_w1[idx]*b_g1[m], dh, dl, (size_t)0 + idx); } break;
    case 3: { // r1 rows 128-255 of merged
      if (idx >= 32768) return; int m = idx >> 8;
      wsplit(r_w1[idx]*r_g1[m], dh, dl, 32768 + (size_t)idx); } break;
    case 1: { // b2 [128][1152] k = tap*128+c
      if (idx >= 147456) return; int m = idx / 1152; int k = idx - m*1152;
      int tap = k >> 7, c = k & 127;
      wsplit(b_w2[((size_t)(m*128 + c))*9 + tap]*b_g2[m], dh, dl, 65536 + (size_t)idx); } break;
    case 2: { // xbase dual [512][384]
      if (idx >= 196608) return; int m = idx / 384; int k = idx - m*384;
      float v = (k < 128) ? b_w3[m*128 + k]*b_g3[m] : b_dw[m*256 + (k-128)]*b_dg[m];
      wsplit(v, dh, dl, 212992 + (size_t)idx); } break;
    case 4: { // r2 [128][1152]
      if (idx >= 147456) return; int m = idx / 1152; int k = idx - m*1152;
      int tap = k >> 7, c = k & 127;
      wsplit(r_w2[((size_t)(m*128 + c))*9 + tap]*r_g2[m], dh, dl, 409600 + (size_t)idx); } break;
    case 5: { // fuse dual [512][384]
      if (idx >= 196608) return; int m = idx / 384; int k = idx - m*384;
      float v = (k < 128) ? r_w3[m*128 + k]*r_g3[m] : r_dw[m*256 + (k-128)]*r_dg[m];
      wsplit(v, dh, dl, 557056 + (size_t)idx); } break;
    case 6: { // f1 [128][512]
      if (idx >= 65536) return; int m = idx >> 9;
      wsplit(f_w1[idx]*f_g1[m], dh, dl, 753664 + (size_t)idx); } break;
    case 7: { // f2 [128][1152]
      if (idx >= 147456) return; int m = idx / 1152; int k = idx - m*1152;
      int tap = k >> 7, c = k & 127;
      wsplit(f_w2[((size_t)(m*128 + c))*9 + tap]*f_g2[m], dh, dl, 819200 + (size_t)idx); } break;
    case 8: { // final [512][128]
      if (idx >= 65536) return; int m = idx >> 7;
      wsplit(f_w3[idx]*f_g3[m], dh, dl, 966656 + (size_t)idx); } break;
    case 9: { // zero page + concat bias
      if (idx < 64) zp[idx] = 0;
      if (idx < 128) biasC[idx] = b_b1[idx];
      else if (idx < 256) biasC[idx] = r_b1[idx-128];
    } break;
  }
}

// ============ pooled: avgpool3s2(x) NCHW f32 -> NHWC hi/lo, fused transpose ============
__global__ __launch_bounds__(256) void k_pool2(const float* __restrict__ x,
    ushortT* __restrict__ ph_, ushortT* __restrict__ pl_){
  __shared__ float s[16][17];
  const int p0 = blockIdx.x*16, c0 = blockIdx.y*16, bz = blockIdx.z;
  const int ci = threadIdx.x >> 4, pi = threadIdx.x & 15;
  {
    const int p = p0 + pi;
    const int oy = p / WP, ox = p - oy*WP;
    const float* src = x + ((size_t)bz*CINX + c0 + ci)*HWX;
    float sum = 0.f;
    #pragma unroll
    for (int dy=0; dy<3; dy++){
      int yy = 2*oy-1+dy;
      if ((unsigned)yy >= HH) continue;
      #pragma unroll
      for (int dx=0; dx<3; dx++){
        int xx = 2*ox-1+dx;
        if ((unsigned)xx >= WW) continue;
        sum += src[yy*WW + xx];
      }
    }
    s[ci][pi] = sum * (1.f/9.f);
  }
  __syncthreads();
  const int pr = threadIdx.x >> 4, cj = threadIdx.x & 15;
  float v = s[cj][pr];
  ushortT h, lo; split2(v, h, lo);
  size_t o = ((size_t)bz*HWP + p0 + pr)*CINX + c0 + cj;
  ph_[o] = h; pl_[o] = lo;
}

// ============ x f32 NCHW -> NHWC hi/lo (16x16 LDS transpose) ============
__global__ __launch_bounds__(256) void prep_x2(const float* __restrict__ x,
    ushortT* __restrict__ xh, ushortT* __restrict__ xl){
  __shared__ float s[16][17];
  const int p0 = blockIdx.x*16, c0 = blockIdx.y*16, bz = blockIdx.z;
  const int ci = threadIdx.x >> 4, pi = threadIdx.x & 15;
  s[ci][pi] = x[((size_t)bz*CINX + c0 + ci)*HWX + p0 + pi];
  __syncthreads();
  const int pr = threadIdx.x >> 4, cj = threadIdx.x & 15;
  float v = s[cj][pr];
  ushortT h, lo; split2(v, h, lo);
  size_t o = ((size_t)bz*HWX + p0 + pr)*CINX + c0 + cj;
  xh[o] = h; xl[o] = lo;
}

// ============ avgpool 3x3 s2 p1 on fused (NHWC hi/lo) -> f32 NHWC [bz][p][512] ============
__global__ __launch_bounds__(256) void k_poolf(const ushortT* __restrict__ fzh,
    const ushortT* __restrict__ fzl, float* __restrict__ pf){
  const int pb = blockIdx.x, bz = blockIdx.y;
  const int psub = threadIdx.x >> 6;
  const int lane = threadIdx.x & 63;
  const int p = pb*4 + psub;
  const int oy = p / WP, ox = p - oy*WP;
  const int c = lane*8;
  float s[8] = {0.f,0.f,0.f,0.f,0.f,0.f,0.f,0.f};
  #pragma unroll
  for (int dy=0; dy<3; dy++){
    const int iy = 2*oy - 1 + dy;
    if ((unsigned)iy >= (unsigned)HH) continue;
    #pragma unroll
    for (int dx=0; dx<3; dx++){
      const int ix = 2*ox - 1 + dx;
      if ((unsigned)ix >= (unsigned)WW) continue;
      const size_t fi = ((size_t)bz*HWX + (size_t)(iy*WW + ix))*CO + c;
      uint4 hh = *(const uint4*)(fzh + fi);
      uint4 ll = *(const uint4*)(fzl + fi);
      ushortT hv[8], lv[8];
      *(uint4*)hv = hh; *(uint4*)lv = ll;
      #pragma unroll
      for (int j=0;j<8;j++) s[j] += bf2f(hv[j]) + bf2f(lv[j]);
    }
  }
  const size_t o = ((size_t)bz*HWP + p)*CO + c;
  float4 o0 = make_float4(s[0]*(1.f/9.f), s[1]*(1.f/9.f), s[2]*(1.f/9.f), s[3]*(1.f/9.f));
  float4 o1 = make_float4(s[4]*(1.f/9.f), s[5]*(1.f/9.f), s[6]*(1.f/9.f), s[7]*(1.f/9.f));
  *(float4*)(pf + o)     = o0;
  *(float4*)(pf + o + 4) = o1;
}

// ============ unified bf16x3-split MFMA implicit-GEMM (v11: MT=64 option for small-N convs) ============
// MT=64/NWV=4: wave grid 1x4 (WNs=4, NF=2), LDS 48KB dbuf -> 3 blocks/CU, 2x grid.
// Other configs identical to round-14 (counted-vmcnt dbuf, setprio, direct stores).
template<int KIND,int EPI,int S1F,int MT,int NWV,int DBUF,int SWAP,int GX,int GY,
         int STRIDE,int PAD,int HIN,int WIN,int WOUT,int NOUT,int C1,int C2,
         int BSTR1,int MTOT,int KTOT>
__global__ __launch_bounds__(NWV*64)
void gemm_bf3(const ushortT* __restrict__ wph, const ushortT* __restrict__ wpl,
              const ushortT* __restrict__ s1h, const ushortT* __restrict__ s1l,
              const ushortT* __restrict__ s2h, const ushortT* __restrict__ s2l,
              const float* __restrict__ xf32,
              const float* __restrict__ bias1, const float* __restrict__ bias2,
              const float* __restrict__ maskf, const float* __restrict__ xbase,
              const ushortT* __restrict__ zp,
              ushortT* __restrict__ oh, ushortT* __restrict__ ol,
              float* __restrict__ of32)
{
  constexpr int ACALLS  = (MT/(16*NWV) > 0) ? MT/(16*NWV) : 1;  // A glds calls/wave/plane
  constexpr int BCALLS2 = 8/NWV;         // B glds calls/wave/plane
  constexpr int GLDS_PER = (ACALLS + BCALLS2)*2;
  constexpr bool GATHER1 = (KIND==0 && S1F==1);
  constexpr int BUFSZ = MT*64 + 8192;    // ushorts per buffer
  constexpr int WNs = (MT==256) ? 2 : ((MT==64) ? 4 : (NWV==8 ? 4 : 2));
  constexpr int NF  = 128/(WNs*16);      // n-frags per wave
  constexpr int T = GX*GY*BB;
  static_assert(T % 8 == 0, "grid not divisible by 8 XCDs");
  constexpr int QX = T/8;
  __shared__ ushortT smem[BUFSZ*(DBUF+1)];

  const int tid = threadIdx.x;
  const int lin = blockIdx.x;
  const int virt = (lin & 7)*QX + (lin >> 3);        // bijective XCD-chunked remap
  const int vx = virt % GX;
  const int vrest = virt / GX;
  const int vy = vrest % GY;
  const int bz = vrest / GY;
  const int nt = SWAP ? vy : vx;
  const int mt = SWAP ? vx : vy;
  const int l  = tid & 63, w = tid >> 6;
  const int wm = w / WNs, wn = w % WNs;

  // ---- A glds precompute ----
  size_t a_src[2]; int a_dst[2];
  #pragma unroll
  for (int c=0;c<ACALLS;c++){
    int s = (w*ACALLS + c)*64 + l;
    int row = s >> 2, slotm = s & 3;
    int logical = slotm ^ ((row >> 1) & 3);
    a_src[c] = (size_t)(mt*MT + row)*KTOT + logical*8;
    a_dst[c] = (w*ACALLS + c)*512;
  }

  // ---- B glds precompute ----
  int b_dst[2]; size_t b_base1[2], b_base2[2]; int b_klane[2];
  int b_oy[2], b_ox[2]; bool b_ok[2]; float b_mv[2];
  #pragma unroll
  for (int c=0;c<BCALLS2;c++){
    int s = (w*BCALLS2 + c)*64 + l;
    int row = s >> 2, slotm = s & 3;
    int logical = slotm ^ ((row >> 1) & 3);
    b_klane[c] = logical*8;
    b_dst[c] = (w*BCALLS2 + c)*512;
    int ngr = nt*128 + row;
    b_ok[c] = (ngr < NOUT);
    int oyv = ngr / WOUT, oxv = ngr - (ngr / WOUT)*WOUT;
    b_oy[c] = oyv; b_ox[c] = oxv;
    b_base1[c] = ((size_t)bz*NOUT + ngr)*BSTR1 + b_klane[c];
    b_base2[c] = ((size_t)bz*NOUT + ngr)*C2 + b_klane[c];
    b_mv[c] = 1.f;
    if (KIND == 3)
      b_mv[c] = b_ok[c] ? maskf[((size_t)(bz*NG + mt)*MSZ + (oyv>>3))*MSZ + (oxv>>3)] : 0.f;
  }

  // ---- gather-path ids: ALL threads, 8 elems each (one 16B slot) ----
  const int g_sr = tid >> 2;
  const int g_hq = tid & 3;
  const int g_swz = (g_sr >> 1) & 3;
  const int g_lws = g_sr*32 + (g_hq ^ g_swz)*8;
  const int g_ng = nt*128 + g_sr;

  f32x4 acc[4][4];
  f32x4 zf = {0.f,0.f,0.f,0.f};
  #pragma unroll
  for (int i=0;i<4;i++)
    #pragma unroll
    for (int j=0;j<4;j++) acc[i][j] = zf;

  auto stagef = [&](int ks, ushortT* AHb, ushortT* ALb, ushortT* BHb, ushortT* BLb){
    const int k0 = ks*32;
    #pragma unroll
    for (int c=0;c<ACALLS;c++){
      glds16(wph + a_src[c] + k0, AHb + a_dst[c]);
      glds16(wpl + a_src[c] + k0, ALb + a_dst[c]);
    }
    if constexpr (GATHER1){
      uint4 bh4 = make_uint4(0,0,0,0), bl4 = bh4;
      if (g_ng < NOUT){
        size_t fbase = ((size_t)bz*C1 + k0 + g_hq*8)*(size_t)NOUT + g_ng;
        ushortT h[8], lo[8];
        #pragma unroll
        for (int e=0;e<8;e++){ split2(xf32[fbase + (size_t)e*NOUT], h[e], lo[e]); }
        bh4 = make_uint4(packu(h[0],h[1]),  packu(h[2],h[3]),  packu(h[4],h[5]),  packu(h[6],h[7]));
        bl4 = make_uint4(packu(lo[0],lo[1]),packu(lo[2],lo[3]),packu(lo[4],lo[5]),packu(lo[6],lo[7]));
      }
      *(uint4*)(BHb + g_lws) = bh4;
      *(uint4*)(BLb + g_lws) = bl4;
    } else {
      #pragma unroll
      for (int c=0;c<BCALLS2;c++){
        const ushortT *sh, *sl;
        if constexpr (KIND == 0){
          bool ok = b_ok[c];
          size_t off = b_base1[c] + k0;
          sh = ok ? s1h + off : zp;  sl = ok ? s1l + off : zp;
        } else if constexpr (KIND == 1){
          const int tap = k0 >> 7;             // C1 == 128
          const int cb  = (k0 & 127);
          const int dy = tap/3, dx = tap - 3*(tap/3);
          int iy = b_oy[c]*STRIDE + dy - PAD;
          int ix = b_ox[c]*STRIDE + dx - PAD;
          bool ok = b_ok[c] && (unsigned)iy < (unsigned)HIN && (unsigned)ix < (unsigned)WIN;
          size_t off = ((size_t)bz*(HIN*WIN) + (size_t)(iy*WIN + ix))*BSTR1 + cb + b_klane[c];
          sh = ok ? s1h + off : zp;  sl = ok ? s1l + off : zp;
        } else {
          if (k0 < C1){
            bool ok = b_ok[c] && (KIND != 3 || b_mv[c] != 0.f);
            size_t off = b_base1[c] + k0;
            sh = ok ? s1h + off : zp;  sl = ok ? s1l + off : zp;
          } else {
            bool ok = b_ok[c];
            size_t off = b_base2[c] + (k0 - C1);
            sh = ok ? s2h + off : zp;  sl = ok ? s2l + off : zp;
          }
        }
        glds16(sh, BHb + b_dst[c]);
        glds16(sl, BLb + b_dst[c]);
      }
    }
  };

  auto computef = [&](const ushortT* AHb, const ushortT* ALb,
                      const ushortT* BHb, const ushortT* BLb){
    short8 bh[NF], bl[NF];
    #pragma unroll
    for (int nf=0; nf<NF; nf++){
      const int rr = wn*(NF*16) + nf*16 + (l & 15);
      const int ph = (l >> 4) ^ ((rr >> 1) & 3);
      bh[nf] = *(const short8*)(BHb + rr*32 + ph*8);
      bl[nf] = *(const short8*)(BLb + rr*32 + ph*8);
    }
    __builtin_amdgcn_s_setprio(1);
    #pragma unroll
    for (int mf=0; mf<4; mf++){
      const int rr = wm*64 + mf*16 + (l & 15);
      const int ph = (l >> 4) ^ ((rr >> 1) & 3);
      short8 ah = *(const short8*)(AHb + rr*32 + ph*8);
      short8 al = *(const short8*)(ALb + rr*32 + ph*8);
      #pragma unroll
      for (int nf=0; nf<NF; nf++)
        acc[mf][nf] = __builtin_amdgcn_mfma_f32_16x16x32_bf16(ah, bh[nf], acc[mf][nf], 0,0,0);
      #pragma unroll
      for (int nf=0; nf<NF; nf++)
        acc[mf][nf] = __builtin_amdgcn_mfma_f32_16x16x32_bf16(ah, bl[nf], acc[mf][nf], 0,0,0);
      #pragma unroll
      for (int nf=0; nf<NF; nf++)
        acc[mf][nf] = __builtin_amdgcn_mfma_f32_16x16x32_bf16(al, bh[nf], acc[mf][nf], 0,0,0);
    }
    __builtin_amdgcn_s_setprio(0);
  };

  const int NK = KTOT / 32;
  if constexpr (DBUF == 0){
    ushortT* AH  = smem;
    ushortT* AL  = smem + MT*32;
    ushortT* BHs = smem + MT*64;
    ushortT* BLs = smem + MT*64 + 4096;
    for (int ks=0; ks<NK; ks++){
      stagef(ks, AH, AL, BHs, BLs);
      __syncthreads();
      computef(AH, AL, BHs, BLs);
      __syncthreads();
    }
  } else {
    // counted-vmcnt pipeline: next-stage glds stay in flight across barriers + MFMA
    stagef(0, smem, smem + MT*32, smem + MT*64, smem + MT*64 + 4096);
    asm volatile("s_waitcnt vmcnt(0)" ::: "memory");
    __builtin_amdgcn_s_barrier();
    for (int ks=0; ks<NK; ks++){
      ushortT* cb = smem + (ks & 1)*BUFSZ;
      ushortT* nb = smem + ((ks & 1) ^ 1)*BUFSZ;
      if (ks + 1 < NK){
        stagef(ks + 1, nb, nb + MT*32, nb + MT*64, nb + MT*64 + 4096);
        if constexpr (GLDS_PER == 4)
          asm volatile("s_waitcnt vmcnt(4)" ::: "memory");
        else if constexpr (GLDS_PER == 6)
          asm volatile("s_waitcnt vmcnt(6)" ::: "memory");
        else
          asm volatile("s_waitcnt vmcnt(8)" ::: "memory");
      } else {
        asm volatile("s_waitcnt vmcnt(0)" ::: "memory");
      }
      __builtin_amdgcn_sched_barrier(0);
      __builtin_amdgcn_s_barrier();
      computef(cb, cb + MT*32, cb + MT*64, cb + MT*64 + 4096);
      __builtin_amdgcn_s_barrier();
    }
  }

  // epilogue (direct stores): C/D frag col n = l&15, row m = (l>>4)*4+r
  const int mb0 = mt*MT + wm*64;
  const int nb0 = nt*128 + wn*(NF*16);

  #pragma unroll
  for (int nf=0; nf<NF; nf++){
    const int n = nb0 + nf*16 + (l & 15);
    if (n >= NOUT) continue;
    if constexpr (EPI == 0){
      const size_t ob = ((size_t)bz*NOUT + n)*MTOT;
      #pragma unroll
      for (int mf=0; mf<4; mf++){
        const int m0 = mb0 + mf*16 + (l>>4)*4;
        ushort4 hq, lq; ushortT h0, l0; float v;
        v = fmaxf(acc[mf][nf][0] + bias1[m0+0], 0.f); split2(v,h0,l0); hq.x=h0; lq.x=l0;
        v = fmaxf(acc[mf][nf][1] + bias1[m0+1], 0.f); split2(v,h0,l0); hq.y=h0; lq.y=l0;
        v = fmaxf(acc[mf][nf][2] + bias1[m0+2], 0.f); split2(v,h0,l0); hq.z=h0; lq.z=l0;
        v = fmaxf(acc[mf][nf][3] + bias1[m0+3], 0.f); split2(v,h0,l0); hq.w=h0; lq.w=l0;
        *(ushort4*)(oh + ob + m0) = hq;
        *(ushort4*)(ol + ob + m0) = lq;
      }
    } else if constexpr (EPI == 1){
      #pragma unroll
      for (int mf=0; mf<4; mf++){
        const int m0 = mb0 + mf*16 + (l>>4)*4;
        #pragma unroll
        for (int r=0;r<4;r++){
          const int m = m0 + r;
          of32[((size_t)bz*MTOT + m)*NOUT + n] = acc[mf][nf][r] + bias1[m] + bias2[m];
        }
      }
    } else if constexpr (EPI == 2){
      const int y = n / WOUT, x = n - (n / WOUT)*WOUT;
      const int grpw = (mt*MT + wm*64) >> 7;
      const float mvv = maskf[((size_t)(bz*NG + grpw)*MSZ + (y>>3))*MSZ + (x>>3)];
      const int iy = y >> 1, ix = x >> 1;
      int yA,yB,xA,xB; float wyA,wyB,wxA,wxB;
      if (y & 1){ yA=iy; wyA=0.75f; yB=(iy+1<HP)?iy+1:HP-1; wyB=0.25f; }
      else      { yA=(iy>0)?iy-1:0; wyA=0.25f; yB=iy; wyB=0.75f; }
      if (x & 1){ xA=ix; wxA=0.75f; xB=(ix+1<WP)?ix+1:WP-1; wxB=0.25f; }
      else      { xA=(ix>0)?ix-1:0; wxA=0.25f; xB=ix; wxB=0.75f; }
      const size_t ob = ((size_t)bz*NOUT + n)*MTOT;
      #pragma unroll
      for (int mf=0; mf<4; mf++){
        const int m0 = mb0 + mf*16 + (l>>4)*4;
        ushort4 hq, lq;
        #pragma unroll
        for (int r=0;r<4;r++){
          const int m = m0 + r;
          const float* xb = xbase + ((size_t)bz*MTOT + m)*HWP;
          float up = wyA*(wxA*xb[yA*WP+xA] + wxB*xb[yA*WP+xB])
                   + wyB*(wxA*xb[yB*WP+xA] + wxB*xb[yB*WP+xB]);
          float v = fmaxf(acc[mf][nf][r] + up + mvv*bias1[m] + bias2[m], 0.f);
          ushortT h0, l0; split2(v, h0, l0);
          if      (r==0){hq.x=h0;lq.x=l0;}
          else if (r==1){hq.y=h0;lq.y=l0;}
          else if (r==2){hq.z=h0;lq.z=l0;}
          else          {hq.w=h0;lq.w=l0;}
        }
        *(ushort4*)(oh + ob + m0) = hq;
        *(ushort4*)(ol + ob + m0) = lq;
      }
    } else { // EPI == 3: out = relu(acc + bias1 + pooledF[bz][n][m])
      const float* pfrow = xbase + ((size_t)bz*NOUT + n)*MTOT;
      #pragma unroll
      for (int mf=0; mf<4; mf++){
        const int m0 = mb0 + mf*16 + (l>>4)*4;
        const float4 pv = *(const float4*)(pfrow + m0);
        of32[((size_t)bz*MTOT + m0+0)*NOUT + n] = fmaxf(acc[mf][nf][0] + bias1[m0+0] + pv.x, 0.f);
        of32[((size_t)bz*MTOT + m0+1)*NOUT + n] = fmaxf(acc[mf][nf][1] + bias1[m0+1] + pv.y, 0.f);
        of32[((size_t)bz*MTOT + m0+2)*NOUT + n] = fmaxf(acc[mf][nf][2] + bias1[m0+2] + pv.z, 0.f);
        of32[((size_t)bz*MTOT + m0+3)*NOUT + n] = fmaxf(acc[mf][nf][3] + bias1[m0+3] + pv.w, 0.f);
      }
    }
  }
}

// ============ gmap v2 (round-6 proven) ============
#define GM_LDSW 9216
__global__ __launch_bounds__(256) void k_gmap2(const float* __restrict__ xbase,
    const float* __restrict__ mw, const float* __restrict__ mg, const float* __restrict__ mb,
    float* __restrict__ gmap){
  __shared__ float wsh[GM_LDSW];
  __shared__ float red[16][2][4][16];
  const int tile = blockIdx.x, b = blockIdx.y;
  const int tid = threadIdx.x;
  const int pl = tid & 15, cs = tid >> 4;
  const int p = tile*16 + pl;
  const int oy = p / WP, ox = p - oy*WP;
  int toff[9];
  #pragma unroll
  for (int tap=0; tap<9; tap++){
    int dy = tap/3, dx = tap - 3*dy;
    int yy = oy + dy - 1, xx = ox + dx - 1;
    toff[tap] = ((unsigned)yy < (unsigned)HP && (unsigned)xx < (unsigned)WP) ? (yy*WP + xx) : -1;
  }
  float acc[2][4] = {{0.f,0.f,0.f,0.f},{0.f,0.f,0.f,0.f}};
  for (int pass=0; pass<2; pass++){
    __syncthreads();
    for (int i = tid; i < GM_LDSW; i += 256){
      int ocl = i & 3, tap = (i >> 2) % 9, c_rel = i / 36;
      int cg = pass*256 + c_rel;
      int g = cg >> 7;
      int oc = g*4 + ocl;
      wsh[i] = mw[((size_t)(oc*128 + (cg & 127)))*9 + tap] * mg[oc];
    }
    __syncthreads();
    const float* xb = xbase + ((size_t)b*CO + pass*256 + cs*16)*HWP;
    for (int cl=0; cl<16; cl++){
      const float* xc = xb + (size_t)cl*HWP;
      const float* wr = &wsh[(cs*16 + cl)*36];
      #pragma unroll
      for (int tap=0; tap<9; tap++){
        if (toff[tap] < 0) continue;
        float v = xc[toff[tap]];
        f32x4 w4 = *(const f32x4*)(wr + tap*4);
        acc[pass][0] += v*w4[0];
        acc[pass][1] += v*w4[1];
        acc[pass][2] += v*w4[2];
        acc[pass][3] += v*w4[3];
      }
    }
  }
  #pragma unroll
  for (int pp=0; pp<2; pp++)
    #pragma unroll
    for (int o=0; o<4; o++)
      red[cs][pp][o][pl] = acc[pp][o];
  __syncthreads();
  const int oc = tid >> 4;
  const int g = oc >> 2, ocl = oc & 3, pg = g >> 1, cs0 = (g & 1)*8;
  float s = 0.f;
  #pragma unroll
  for (int t=0; t<8; t++) s += red[cs0 + t][pg][ocl][pl];
  s = fmaxf(s + mb[oc], 0.f);
  gmap[((size_t)b*16 + oc)*HWP + p] = s;
}

__global__ __launch_bounds__(256) void k_gpool(const float* __restrict__ gmap, float* __restrict__ gpool){
  int idx = blockIdx.x*256 + threadIdx.x;
  if (idx >= BB*16*49) return;
  int q = idx % 49; int t = idx / 49; int ch = t % 16; int b = t / 16;
  int my = q/7, mx = q%7;
  const float* src = gmap + ((size_t)b*16 + ch)*HWP;
  float s = 0.f;
  #pragma unroll
  for (int yb=0;yb<4;yb++)
    #pragma unroll
    for (int xb=0;xb<4;xb++)
      s += src[(my*4+yb)*WP + (mx*4+xb)];
  gpool[idx] = s * (1.f/16.f);
}

__global__ __launch_bounds__(256) void k_mask(const float* __restrict__ gpool, const float* __restrict__ fcw,
    const float* __restrict__ fcb, const float* __restrict__ gum,
    float* __restrict__ maskf, float* __restrict__ mout){
  int idx = blockIdx.x*256 + threadIdx.x;
  if (idx >= BB*NG*49) return;
  int q = idx % 49; int t = idx / 49; int g = t % NG; int b = t / NG;
  float lgt[2];
  #pragma unroll
  for (int cls=0; cls<2; cls++){
    int c = cls*NG + g;
    int gc = c >> 1;
    float s = fcb[c];
    #pragma unroll
    for (int k=0;k<4;k++)
      s += fcw[c*4+k] * gpool[((size_t)b*16 + gc*4 + k)*49 + q];
    s += gum[(((size_t)b*2 + cls)*NG + g)*49 + q];
    lgt[cls] = s;
  }
  float m = (lgt[1] > lgt[0]) ? 1.f : 0.f;
  maskf[idx] = m;
  mout[idx] = m;
}

extern "C" void kernel_launch(void* const* d_in, const int* in_sizes, int n_in,
                              void* d_out, int out_size, void* d_ws, size_t ws_size,
                              hipStream_t stream){
  const float* x    = (const float*)d_in[0];
  const float* gum  = (const float*)d_in[1];
  const float* b_w1 = (const float*)d_in[2];
  const float* b_g1 = (const float*)d_in[3];
  const float* b_b1 = (const float*)d_in[4];
  const float* b_w2 = (const float*)d_in[5];
  const float* b_g2 = (const float*)d_in[6];
  const float* b_b2 = (const float*)d_in[7];
  const float* b_w3 = (const float*)d_in[8];
  const float* b_g3 = (const float*)d_in[9];
  const float* b_b3 = (const float*)d_in[10];
  const float* b_dw = (const float*)d_in[11];
  const float* b_dg = (const float*)d_in[12];
  const float* b_db = (const float*)d_in[13];
  const float* r_w1 = (const float*)d_in[14];
  const float* r_g1 = (const float*)d_in[15];
  const float* r_b1 = (const float*)d_in[16];
  const float* r_w2 = (const float*)d_in[17];
  const float* r_g2 = (const float*)d_in[18];
  const float* r_b2 = (const float*)d_in[19];
  const float* r_w3 = (const float*)d_in[20];
  const float* r_g3 = (const float*)d_in[21];
  const float* r_b3 = (const float*)d_in[22];
  const float* r_dw = (const float*)d_in[23];
  const float* r_dg = (const float*)d_in[24];
  const float* r_db = (const float*)d_in[25];
  const float* m_w  = (const float*)d_in[26];
  const float* m_g  = (const float*)d_in[27];
  const float* m_b  = (const float*)d_in[28];
  const float* m_fcw= (const float*)d_in[29];
  const float* m_fcb= (const float*)d_in[30];
  const float* f_w1 = (const float*)d_in[31];
  const float* f_g1 = (const float*)d_in[32];
  const float* f_b1 = (const float*)d_in[33];
  const float* f_w2 = (const float*)d_in[34];
  const float* f_g2 = (const float*)d_in[35];
  const float* f_b2 = (const float*)d_in[36];
  const float* f_w3 = (const float*)d_in[37];
  const float* f_g3 = (const float*)d_in[38];
  const float* f_b3 = (const float*)d_in[39];

  char* ws = (char*)d_ws;
  // ws layout v5 — total 378,367,616 B
  constexpr size_t O_WPH  = 0;            //  2,064,384
  constexpr size_t O_WPL  = 2064384;      //  2,064,384  -> 4,128,768
  constexpr size_t O_CH   = 4128768;      // 51,380,224  merged hi; then XH (x hi NHWC); then f1 hi+lo
  constexpr size_t O_DH   = 55508992;     //  6,422,528  t2/f2 hi
  constexpr size_t O_DL   = 61931520;     //  6,422,528  -> 68,354,048
  constexpr size_t O_EH   = 68354048;     // 25,690,112  r2 hi
  constexpr size_t O_EL   = 94044160;     // 25,690,112  -> 119,734,272
  constexpr size_t O_PF   = O_EH;         // 51,380,224  pooledF f32 NHWC (r2 dead after fuse)
  constexpr size_t O_XB   = 119734272;    // 51,380,224  xbase f32 NCHW
  constexpr size_t O_GMAP = 171114496;    //  1,605,632
  constexpr size_t O_GPOOL= 172720128;    //    100,352
  constexpr size_t O_MASK = 172820480;    //     25,088
  constexpr size_t O_FH   = 172845568;    // 102,760,448 fused hi (overlaps PH/PL)
  constexpr size_t O_PH   = 172845568;    // 12,845,056  pooled hi (dead after xbase GEMM)
  constexpr size_t O_PL   = 185690624;    // 12,845,056
  constexpr size_t O_FL   = 275606016;    // 102,760,448 -> 378,366,464
  constexpr size_t O_ZP   = 378366464;    //        128  zero page
  constexpr size_t O_BIASC= 378366592;    //      1,024  concat bias -> 378,367,616

  ushortT* WPH = (ushortT*)(ws + O_WPH);
  ushortT* WPL = (ushortT*)(ws + O_WPL);
  ushortT* MGH = (ushortT*)(ws + O_CH);          // merged hi plane, stride 256 (b2/r2 input)
  ushortT* XH  = (ushortT*)(ws + O_CH);          // x hi NHWC (after r2; fuse input)
  ushortT* F1H = (ushortT*)(ws + O_CH);          // f1 hi (after fuse)
  ushortT* F1L = (ushortT*)(ws + O_CH + 25690112);
  ushortT* DHp = (ushortT*)(ws + O_DH);
  ushortT* DLp = (ushortT*)(ws + O_DL);
  ushortT* EHp = (ushortT*)(ws + O_EH);
  ushortT* ELp = (ushortT*)(ws + O_EL);
  float*   PF  = (float*)(ws + O_PF);
  float*   XB  = (float*)(ws + O_XB);
  ushortT* PHp = (ushortT*)(ws + O_PH);
  ushortT* PLp = (ushortT*)(ws + O_PL);
  ushortT* FHp = (ushortT*)(ws + O_FH);
  ushortT* FLp = (ushortT*)(ws + O_FL);
  float*   GMAP = (float*)(ws + O_GMAP);
  float*   GPOOL= (float*)(ws + O_GPOOL);
  float*   MASKF= (float*)(ws + O_MASK);
  ushortT* ZP  = (ushortT*)(ws + O_ZP);
  float*   BIASC = (float*)(ws + O_BIASC);
  (void)ws_size;

  float* outp = (float*)d_out;
  float* mout = outp + (size_t)BB*CO*HWP;
  ushortT* dout_u = (ushortT*)d_out;             // merged lo plane, then XL (x lo NHWC)

  dim3 blk(256), blk512(512);
  const ushortT* nu = nullptr; const float* nf_ = nullptr;
  ushortT* nuo = nullptr; float* nfo = nullptr;

  // prep
  prep_w<<<dim3(768, 10), blk, 0, stream>>>(b_w1,b_g1,b_w2,b_g2,b_w3,b_g3,b_dw,b_dg,
      r_w1,r_g1,r_w2,r_g2,r_w3,r_g3,r_dw,r_dg,f_w1,f_g1,f_w2,f_g2,f_w3,f_g3,
      b_b1, r_b1, WPH, WPL, ZP, BIASC);
  k_pool2<<<dim3(49, 16, BB), blk, 0, stream>>>(x, PHp, PLp);

  // merged b1|r1: one x-gather pass (spread over 512 threads), MT=256, 8 waves  T=800
  gemm_bf3<0,0,1,256,8,0,0, 25,1, 1,0,56,56,56,3136, 256,0,256, 256,256><<<dim3(800), blk512, 0, stream>>>(
      WPH+0, WPL+0, nu, nu, nu, nu, x, BIASC, nf_, nf_, nf_, ZP, MGH, dout_u, nfo);
  // b2 — MT=64, 4 waves, counted-vmcnt dbuf, 3 blocks/CU  T=448
  gemm_bf3<1,0,0,64,4,1,0, 7,2, 2,1,56,56,28,784, 128,0,256, 128,1152><<<dim3(448), blk, 0, stream>>>(
      WPH+65536, WPL+65536, MGH, dout_u, nu, nu, nf_, b_b2, nf_, nf_, nf_, ZP, DHp, DLp, nfo);
  // xbase dual — MT=256, 8 waves, single-buffer  T=448
  gemm_bf3<2,1,0,256,8,0,0, 7,2, 1,0,28,28,28,784, 128,256,128, 512,384><<<dim3(448), blk512, 0, stream>>>(
      WPH+212992, WPL+212992, DHp, DLp, PHp, PLp, nf_, b_b3, b_db, nf_, nf_, ZP, nuo, nuo, XB);

  // mask path
  k_gmap2<<<dim3(49, BB), blk, 0, stream>>>(XB, m_w, m_g, m_b, GMAP);
  k_gpool<<<dim3(98), blk, 0, stream>>>(GMAP, GPOOL);
  k_mask<<<dim3(25), blk, 0, stream>>>(GPOOL, m_fcw, m_fcb, gum, MASKF, mout);

  // r2 — MT=128, 4 waves, counted-vmcnt dbuf  T=800
  gemm_bf3<1,0,0,128,4,1,0, 25,1, 1,1,56,56,56,3136, 128,0,256, 128,1152><<<dim3(800), blk, 0, stream>>>(
      WPH+409600, WPL+409600, MGH+128, dout_u+128, nu, nu, nf_, r_b2, nf_, nf_, nf_, ZP, EHp, ELp, nfo);

  // pre-split x -> XH (CH region, merged dead) + XL (d_out, merged-lo dead)
  prep_x2<<<dim3(196, 16, BB), blk, 0, stream>>>(x, XH, dout_u);

  // fused — MT=128, 4 waves, counted-vmcnt dbuf, mt-fastest  T=3200
  gemm_bf3<3,2,0,128,4,1,1, 4,25, 1,0,56,56,56,3136, 128,256,128, 512,384><<<dim3(3200), blk, 0, stream>>>(
      WPH+557056, WPL+557056, EHp, ELp, XH, dout_u, nf_, r_b3, r_db, MASKF, XB, ZP, FHp, FLp, nfo);

  // pooledF = avgpool3s2(fused)
  k_poolf<<<dim3(196, BB), blk, 0, stream>>>(FHp, FLp, PF);

  // fuse branch
  gemm_bf3<0,0,0,128,4,1,0, 25,1, 1,0,56,56,56,3136, 512,0,512, 128,512><<<dim3(800), blk, 0, stream>>>(
      WPH+753664, WPL+753664, FHp, FLp, nu, nu, nf_, f_b1, nf_, nf_, nf_, ZP, F1H, F1L, nfo);
  // f2 — MT=64, 4 waves, counted-vmcnt dbuf, 3 blocks/CU  T=448
  gemm_bf3<1,0,0,64,4,1,0, 7,2, 2,1,56,56,28,784, 128,0,128, 128,1152><<<dim3(448), blk, 0, stream>>>(
      WPH+819200, WPL+819200, F1H, F1L, nu, nu, nf_, f_b2, nf_, nf_, nf_, ZP, DHp, DLp, nfo);
  // final — MT=256, 8 waves, single-buffer  T=448
  gemm_bf3<0,3,0,256,8,0,0, 7,2, 1,0,28,28,28,784, 128,0,128, 512,128><<<dim3(448), blk512, 0, stream>>>(
      WPH+966656, WPL+966656, DHp, DLp, nu, nu, nf_, f_b3, nf_, nf_, PF, ZP, nuo, nuo, outp);
}